// Round 4
// baseline (24.578 us; speedup 1.0000x reference)
//
#include <hip/hip_runtime.h>

typedef float v2f __attribute__((ext_vector_type(2)));

#define NATOMS  1024
#define NB      32
#define WPB     4                  // waves per block
#define BLK     (WPB * 64)         // 256 threads
#define BPBATCH 64                 // blocks per batch
#define WAVES   (BPBATCH * WPB)    // 256 waves per batch
#define PPW     ((NATOMS / 2) / WAVES)  // 2 row-pairs per wave

// e = d0*b*exp(p1*(1-b^p2)) = (d0*e^p1) * b * exp2(c1 * exp2(p2*log2 b)),
// c1 = -p1*log2(e).  Class s = t_i + t_j in {0,1,2}; params linear in t_i.
// Non-transcendental math done in packed fp32 (v_pk_*) on element pairs.
__global__ __launch_bounds__(BLK) void reax_partial(
    const int*   __restrict__ Z,
    const float* __restrict__ B,
    const float* __restrict__ d0t,
    const float* __restrict__ p1t,
    const float* __restrict__ p2t,
    float*       __restrict__ ws)
{
    const int b    = blockIdx.y;
    const int wave = blockIdx.x * WPB + (threadIdx.x >> 6);
    const int lane = threadIdx.x & 63;

    const float LOG2E = 1.4426950408889634f;
    const float d0_0 = d0t[4], d0_1 = d0t[5], d0_2 = d0t[8];
    const float p1_0 = p1t[4], p1_1 = p1t[5], p1_2 = p1t[8];
    const float p2_0 = p2t[4], p2_1 = p2t[5], p2_2 = p2t[8];
    const float de_0 = d0_0 * __builtin_amdgcn_exp2f(p1_0 * LOG2E);
    const float de_1 = d0_1 * __builtin_amdgcn_exp2f(p1_1 * LOG2E);
    const float de_2 = d0_2 * __builtin_amdgcn_exp2f(p1_2 * LOG2E);
    const float c1_0 = -p1_0 * LOG2E, c1_1 = -p1_1 * LOG2E, c1_2 = -p1_2 * LOG2E;

    __shared__ float t_shf[NATOMS];     // atom type as float (0.0 / 1.0)
    const int* Zrow = Z + b * NATOMS;
    for (int i = threadIdx.x; i < NATOMS; i += BLK)
        t_shf[i] = (Zrow[i] == 8) ? 1.0f : 0.0f;
    __syncthreads();

    const float* Bb = B + (size_t)b * NATOMS * NATOMS;
    v2f acc01 = {0.0f, 0.0f}, acc23 = {0.0f, 0.0f};
    float tsum = 0.0f;   // scalar tail accumulator

    for (int pp = 0; pp < PPW; ++pp) {
        const int p = wave + pp * WAVES;   // 0..511
        #pragma unroll
        for (int r = 0; r < 2; ++r) {
            const int j = r ? (NATOMS - 1 - p) : p;
            if (j == 0) continue;
            const int tj = (t_shf[j] != 0.0f);
            const float dea = tj ? de_1 : de_0, dde = tj ? (de_2 - de_1) : (de_1 - de_0);
            const float c1a = tj ? c1_1 : c1_0, dc1 = tj ? (c1_2 - c1_1) : (c1_1 - c1_0);
            const float p2a = tj ? p2_1 : p2_0, dp2 = tj ? (p2_2 - p2_1) : (p2_1 - p2_0);

            const float*  Brow  = Bb + (size_t)j * NATOMS;
            const float4* Brow4 = (const float4*)Brow;
            const float4* Trow4 = (const float4*)t_shf;
            const int nv = j >> 2;

            #pragma unroll 2
            for (int v = lane; v < nv; v += 64) {
                const float4 x  = Brow4[v];
                const float4 t4 = Trow4[v];

                const v2f bb01 = {fabsf(x.x), fabsf(x.y)};
                const v2f bb23 = {fabsf(x.z), fabsf(x.w)};
                const v2f t01  = {t4.x, t4.y};
                const v2f t23  = {t4.z, t4.w};

                const v2f p2v01 = t01 * dp2 + p2a;       // v_pk_fma_f32
                const v2f p2v23 = t23 * dp2 + p2a;
                const v2f c1v01 = t01 * dc1 + c1a;
                const v2f c1v23 = t23 * dc1 + c1a;
                const v2f dev01 = t01 * dde + dea;
                const v2f dev23 = t23 * dde + dea;

                const v2f lg01 = {__builtin_amdgcn_logf(bb01.x), __builtin_amdgcn_logf(bb01.y)};
                const v2f lg23 = {__builtin_amdgcn_logf(bb23.x), __builtin_amdgcn_logf(bb23.y)};
                const v2f pa01 = p2v01 * lg01;           // v_pk_mul_f32
                const v2f pa23 = p2v23 * lg23;
                const v2f pw01 = {__builtin_amdgcn_exp2f(pa01.x), __builtin_amdgcn_exp2f(pa01.y)};
                const v2f pw23 = {__builtin_amdgcn_exp2f(pa23.x), __builtin_amdgcn_exp2f(pa23.y)};
                const v2f ea01 = c1v01 * pw01;
                const v2f ea23 = c1v23 * pw23;
                const v2f ex01 = {__builtin_amdgcn_exp2f(ea01.x), __builtin_amdgcn_exp2f(ea01.y)};
                const v2f ex23 = {__builtin_amdgcn_exp2f(ea23.x), __builtin_amdgcn_exp2f(ea23.y)};

                acc01 = (dev01 * bb01) * ex01 + acc01;   // pk_mul + pk_fma
                acc23 = (dev23 * bb23) * ex23 + acc23;
            }
            // tail: up to 3 elements
            const int i = (nv << 2) + lane;
            if (i < j) {
                const float tif = t_shf[i];
                const float bb  = fabsf(Brow[i]);
                const float p2  = fmaf(tif, dp2, p2a);
                const float c1  = fmaf(tif, dc1, c1a);
                const float de  = fmaf(tif, dde, dea);
                const float lg  = __builtin_amdgcn_logf(bb);
                const float pw  = __builtin_amdgcn_exp2f(p2 * lg);
                const float ex  = __builtin_amdgcn_exp2f(c1 * pw);
                tsum = fmaf(de * bb, ex, tsum);
            }
        }
    }

    float sum = (acc01.x + acc01.y) + (acc23.x + acc23.y) + tsum;
    #pragma unroll
    for (int off = 32; off; off >>= 1) sum += __shfl_down(sum, off, 64);
    if (lane == 0) ws[b * WAVES + wave] = sum;
}

// Stage 2: one 64-lane wave per batch reduces the WAVES partials.
__global__ __launch_bounds__(64) void reax_reduce(
    const float* __restrict__ ws, float* __restrict__ out)
{
    const int b = blockIdx.x;
    const int t = threadIdx.x;
    float s = ws[b * WAVES + t]       + ws[b * WAVES + t + 64]
            + ws[b * WAVES + t + 128] + ws[b * WAVES + t + 192];
    #pragma unroll
    for (int off = 32; off; off >>= 1) s += __shfl_down(s, off, 64);
    if (t == 0) out[b] = -s;
}

extern "C" void kernel_launch(void* const* d_in, const int* in_sizes, int n_in,
                              void* d_out, int out_size, void* d_ws, size_t ws_size,
                              hipStream_t stream) {
    const int*   Z   = (const int*)  d_in[0];
    const float* B   = (const float*)d_in[1];
    const float* d0t = (const float*)d_in[2];
    const float* p1t = (const float*)d_in[3];
    const float* p2t = (const float*)d_in[4];
    float* out = (float*)d_out;
    float* ws  = (float*)d_ws;   // NB*WAVES floats, fully rewritten every call

    dim3 grid(BPBATCH, NB);
    reax_partial<<<grid, BLK, 0, stream>>>(Z, B, d0t, p1t, p2t, ws);
    reax_reduce<<<NB, 64, 0, stream>>>(ws, out);
}

// Round 5
// 23.789 us; speedup vs baseline: 1.0332x; 1.0332x over previous
//
#include <hip/hip_runtime.h>

#define NATOMS  1024
#define NB      32
#define WPB     4                  // waves per block
#define BLK     (WPB * 64)         // 256 threads
#define BPBATCH 64                 // blocks per batch
#define WAVES   (BPBATCH * WPB)    // 256 waves per batch
#define PPW     ((NATOMS / 2) / WAVES)  // 2 row-pairs per wave

// e = d0*b*exp(p1*(1-b^p2)) with class s = t_i+t_j in {0,1,2}:
//   e = de * exp2(lg + c1*exp2(p2*lg)),  lg = log2|b|,
//   de = d0*e^p1, c1 = -p1*log2(e).   (b=0 -> lg=-inf -> e=0, matches ref.)
// Params are linear in t_i in {0,1}. Inner loop unrolled 4x so each wave has
// 4 independent global float4 loads in flight (latency hiding).
__global__ __launch_bounds__(BLK, 8) void reax_partial(
    const int*   __restrict__ Z,
    const float* __restrict__ B,
    const float* __restrict__ d0t,
    const float* __restrict__ p1t,
    const float* __restrict__ p2t,
    float*       __restrict__ ws)
{
    const int b    = blockIdx.y;
    const int wave = blockIdx.x * WPB + (threadIdx.x >> 6);
    const int lane = threadIdx.x & 63;

    const float LOG2E = 1.4426950408889634f;
    const float d0_0 = d0t[4], d0_1 = d0t[5], d0_2 = d0t[8];
    const float p1_0 = p1t[4], p1_1 = p1t[5], p1_2 = p1t[8];
    const float p2_0 = p2t[4], p2_1 = p2t[5], p2_2 = p2t[8];
    const float de_0 = d0_0 * __builtin_amdgcn_exp2f(p1_0 * LOG2E);
    const float de_1 = d0_1 * __builtin_amdgcn_exp2f(p1_1 * LOG2E);
    const float de_2 = d0_2 * __builtin_amdgcn_exp2f(p1_2 * LOG2E);
    const float c1_0 = -p1_0 * LOG2E, c1_1 = -p1_1 * LOG2E, c1_2 = -p1_2 * LOG2E;

    __shared__ float t_shf[NATOMS];     // atom type as float (0.0 / 1.0)
    const int* Zrow = Z + b * NATOMS;
    for (int i = threadIdx.x; i < NATOMS; i += BLK)
        t_shf[i] = (Zrow[i] == 8) ? 1.0f : 0.0f;
    __syncthreads();

    const float* Bb = B + (size_t)b * NATOMS * NATOMS;
    float sum0 = 0.0f, sum1 = 0.0f;

    for (int pp = 0; pp < PPW; ++pp) {
        const int p = wave + pp * WAVES;   // 0..511
        #pragma unroll
        for (int r = 0; r < 2; ++r) {
            const int j = r ? (NATOMS - 1 - p) : p;
            if (j == 0) continue;
            const int tj = (t_shf[j] != 0.0f);
            const float dea = tj ? de_1 : de_0, dde = tj ? (de_2 - de_1) : (de_1 - de_0);
            const float c1a = tj ? c1_1 : c1_0, dc1 = tj ? (c1_2 - c1_1) : (c1_1 - c1_0);
            const float p2a = tj ? p2_1 : p2_0, dp2 = tj ? (p2_2 - p2_1) : (p2_1 - p2_0);

            const float*  Brow  = Bb + (size_t)j * NATOMS;
            const float4* Brow4 = (const float4*)Brow;
            const float4* Trow4 = (const float4*)t_shf;
            const int nv = j >> 2;

            #define ELEM(xc, tc, acc)                                       \
            {                                                               \
                const float bb  = fabsf(xc);                                \
                const float p2  = fmaf(tc, dp2, p2a);                       \
                const float c1  = fmaf(tc, dc1, c1a);                       \
                const float de  = fmaf(tc, dde, dea);                       \
                const float lg  = __builtin_amdgcn_logf(bb);                \
                const float pw  = __builtin_amdgcn_exp2f(p2 * lg);          \
                const float ex  = __builtin_amdgcn_exp2f(fmaf(c1, pw, lg)); \
                acc = fmaf(de, ex, acc);                                    \
            }

            #pragma unroll 4
            for (int v = lane; v < nv; v += 64) {
                const float4 x  = Brow4[v];
                const float4 t4 = Trow4[v];
                ELEM(x.x, t4.x, sum0) ELEM(x.y, t4.y, sum1)
                ELEM(x.z, t4.z, sum0) ELEM(x.w, t4.w, sum1)
            }
            // tail: up to 3 elements
            const int i = (nv << 2) + lane;
            if (i < j) {
                ELEM(Brow[i], t_shf[i], sum0)
            }
            #undef ELEM
        }
    }

    float sum = sum0 + sum1;
    #pragma unroll
    for (int off = 32; off; off >>= 1) sum += __shfl_down(sum, off, 64);
    if (lane == 0) ws[b * WAVES + wave] = sum;
}

// Stage 2: one 64-lane wave per batch reduces the WAVES partials.
__global__ __launch_bounds__(64) void reax_reduce(
    const float* __restrict__ ws, float* __restrict__ out)
{
    const int b = blockIdx.x;
    const int t = threadIdx.x;
    float s = ws[b * WAVES + t]       + ws[b * WAVES + t + 64]
            + ws[b * WAVES + t + 128] + ws[b * WAVES + t + 192];
    #pragma unroll
    for (int off = 32; off; off >>= 1) s += __shfl_down(s, off, 64);
    if (t == 0) out[b] = -s;
}

extern "C" void kernel_launch(void* const* d_in, const int* in_sizes, int n_in,
                              void* d_out, int out_size, void* d_ws, size_t ws_size,
                              hipStream_t stream) {
    const int*   Z   = (const int*)  d_in[0];
    const float* B   = (const float*)d_in[1];
    const float* d0t = (const float*)d_in[2];
    const float* p1t = (const float*)d_in[3];
    const float* p2t = (const float*)d_in[4];
    float* out = (float*)d_out;
    float* ws  = (float*)d_ws;   // NB*WAVES floats, fully rewritten every call

    dim3 grid(BPBATCH, NB);
    reax_partial<<<grid, BLK, 0, stream>>>(Z, B, d0t, p1t, p2t, ws);
    reax_reduce<<<NB, 64, 0, stream>>>(ws, out);
}